// Round 28
// baseline (84.378 us; speedup 1.0000x reference)
//
#include <hip/hip_runtime.h>
#include <math.h>

// B=256, P=40, S=60, D=64. Round-28 = Round-27's 2-sequential-parts plan in
// a 256-THREAD WG. Evidence chain: R26/R27 proved any part-loop at 512-thr
// spills (allocator budget 65536/512 = 128; body 112 + loop state > 128 ->
// ~20 MB scratch, the 12-16 us poison). 256-thr budget = 256: R9/R14 looped
// bodies allocated 156-240 there with ZERO spill. Config: 1280 WGs x 256 thr
// (4 waves/WG), 2 parts/wave = 5120 waves; LDS = 40 KB weights + 4 x-tiles
// = 70 KB -> 2 WGs/CU co-resident (8 waves/CU, same as R20's best) with no
// spill possible. Model: WG lifetime ~21 us, 5 WGs/CU at 2 co-resident
// -> ~52 us + ramp.
//
// Register-chain trick: MFMA contraction is invariant to permuting the k-dim.
// C/D output holds the row-dim in-lane as {16mt+4g+j}; the next GEMM
// contracting that dim takes both operands by pure register reindexing:
//     frag[nt][ks] = pk16( acc2[2ks][nb], acc2[2ks+1][nb] )
// map pi(ks,i,g)=16*(2ks+(i>>2))+4g+(i&3). W1/W2 pre-permuted to pi-layout.
//
// Layout facts (cdna4 guide, measured m89/m91):
//   C/D: lane holds col=lane&15, rows 16mt+4(lane>>4)+j
//   A/B: row(col)=lane&15, kappa = 32ks+8(lane>>4)+i

typedef _Float16 half8 __attribute__((ext_vector_type(8)));
typedef __fp16 fp16x2 __attribute__((ext_vector_type(2)));
typedef float f4 __attribute__((ext_vector_type(4)));

#define MFMA16(a, b, c) __builtin_amdgcn_mfma_f32_16x16x32_f16((a), (b), (c), 0, 0, 0)

__global__ __launch_bounds__(256) void prep_weights(
    const float* __restrict__ Wq, const float* __restrict__ Wk,
    const float* __restrict__ Wv, const float* __restrict__ W1,
    const float* __restrict__ W2, _Float16* __restrict__ wsH) {
    int idx = blockIdx.x * 256 + threadIdx.x;  // 0..20479
    int m = idx >> 12, r = idx & 4095;
    const float* src = (m == 0) ? Wq : (m == 1) ? Wk : (m == 2) ? Wv
                        : (m == 3) ? W1 : W2;
    float v;
    if (m < 3) {
        v = src[r];  // natural row-major [e][d]
    } else {
        // pi-permuted: position (e, kappa) holds W[e][ d=16*(2ks+(i>>2))+4g+(i&3) ]
        int e = r >> 6, kp = r & 63;
        int ks = kp >> 5, gg = (kp >> 3) & 3, i = kp & 7;
        int d = 16 * (2 * ks + (i >> 2)) + 4 * gg + (i & 3);
        v = src[e * 64 + d];
    }
    wsH[idx] = (_Float16)v;
}

// Packed f32x4 + f32x4 -> half8 via v_cvt_pkrtz_f16_f32 (4 insts).
__device__ __forceinline__ half8 pk8(f4 a, f4 b) {
    union { half8 h; fp16x2 p[4]; } u;
    u.p[0] = __builtin_amdgcn_cvt_pkrtz(a[0], a[1]);
    u.p[1] = __builtin_amdgcn_cvt_pkrtz(a[2], a[3]);
    u.p[2] = __builtin_amdgcn_cvt_pkrtz(b[0], b[1]);
    u.p[3] = __builtin_amdgcn_cvt_pkrtz(b[2], b[3]);
    return u.h;
}

// Half-width GEMM into acc2[4][2]: output cols nt in {2h, 2h+1}.
// AEXPR uses (t, ks); BEXPR uses (nt, ks); CEXPR uses (mt, nb, nt).
#define GEMM_H(AEXPR, BEXPR, CEXPR)                                          \
    do {                                                                     \
        _Pragma("unroll")                                                    \
        for (int ks = 0; ks < 2; ++ks) {                                     \
            half8 afr[4], bfr[2];                                            \
            _Pragma("unroll")                                                \
            for (int t = 0; t < 4; ++t) afr[t] = (AEXPR);                    \
            _Pragma("unroll")                                                \
            for (int nb = 0; nb < 2; ++nb) {                                 \
                const int nt = 2 * h + nb; (void)nt;                         \
                bfr[nb] = (BEXPR);                                           \
            }                                                                \
            _Pragma("unroll")                                                \
            for (int mt = 0; mt < 4; ++mt)                                   \
                _Pragma("unroll")                                            \
                for (int nb = 0; nb < 2; ++nb) {                             \
                    const int nt = 2 * h + nb; (void)nt;                     \
                    acc2[mt][nb] = MFMA16(afr[mt], bfr[nb],                  \
                                          ks == 0 ? (CEXPR) : acc2[mt][nb]); \
                }                                                            \
        }                                                                    \
    } while (0)

// acc2 -> pi-layout frags for this half (dst[2h+nb][ks]).
#define MKFR_H(dst, RELU)                                                    \
    do {                                                                     \
        _Pragma("unroll")                                                    \
        for (int nb = 0; nb < 2; ++nb)                                       \
            _Pragma("unroll")                                                \
            for (int ks = 0; ks < 2; ++ks) {                                 \
                f4 a_ = acc2[2 * ks][nb], b_ = acc2[2 * ks + 1][nb];         \
                if (RELU) {                                                  \
                    _Pragma("unroll")                                        \
                    for (int j = 0; j < 4; ++j) {                            \
                        a_[j] = fmaxf(a_[j], 0.f);                           \
                        b_[j] = fmaxf(b_[j], 0.f);                           \
                    }                                                        \
                }                                                            \
                dst[2 * h + nb][ks] = pk8(a_, b_);                           \
            }                                                                \
    } while (0)

// Weight fragment from LDS: matrix widx, row-block RB (row = 16*RB+lo),
// kappa chunk (32ks+8g), XOR-swizzled by (lo&7)<<3 halves.
#define WFRAG(widx, RB) (*(const half8*)&wlds[(widx) * 4096 + (16 * (RB) + lo) * 64 + \
                                              ((32 * ks + 8 * g) ^ ((lo & 7) << 3))])

// x fragment from LDS (rows >= 60 -> zero; constant-folds for RB < 3).
#define XFRAG(RB) __extension__({                                            \
    int row_ = 16 * (RB) + lo;                                               \
    int rowc_ = row_ < 60 ? row_ : 48;                                       \
    half8 v_ = *(const half8*)&wlds[xbase + rowc_ * 64 +                     \
                                    ((32 * ks + 8 * g) ^ ((lo & 7) << 3))];  \
    if (row_ >= 60) { half8 z_ = {}; v_ = z_; }                              \
    v_; })

__global__ __launch_bounds__(256, 1) void fused_f16(
    const float* __restrict__ x, const _Float16* __restrict__ wH,
    const float* __restrict__ bq, const float* __restrict__ bk,
    const float* __restrict__ bv, const float* __restrict__ b1,
    const float* __restrict__ b2, const float* __restrict__ W3,
    const float* __restrict__ b3, float* __restrict__ out) {
    // 40 KB weights + 4 x-tiles (60x64 f16, swizzled) = 71680 B = 70 KB.
    __shared__ __align__(16) _Float16 wlds[35840];

    const int tid = threadIdx.x;
    const int l = tid & 63;           // lane
    const int w = tid >> 6;           // wave 0..3 (TWO sequential parts each)
    const int lo = l & 15, g = l >> 4;

    // ---- cooperative weight load global->LDS with write-side swizzle.
    #pragma unroll
    for (int rep = 0; rep < 10; ++rep) {
        int chunk = rep * 256 + tid;          // 0..2559
        int widx = chunk >> 9;
        int rem = chunk & 511;
        int row = rem >> 3, c = rem & 7;
        *(half8*)&wlds[widx * 4096 + row * 64 + ((c * 8) ^ ((row & 7) << 3))] =
            *(const half8*)&wH[widx * 4096 + row * 64 + c * 8];
    }
    __syncthreads();  // weights visible to all; waves independent afterwards

    const int part0 = blockIdx.x * 8 + w * 2;   // two consecutive parts
    const int xbase = 20480 + w * 3840;         // x tile reused per iteration

    #pragma unroll 1
    for (int it = 0; it < 2; ++it) {
        // Pin the back-edge: iteration it+1's loads may not hoist into it.
        __builtin_amdgcn_sched_barrier(0);

        const int part = part0 + it;
        const float* __restrict__ xp = x + (size_t)part * (60 * 64);

        // ---- stage this part's x into LDS (f16, swizzled). Same-wave
        // in-order LDS: this iteration's writes follow prior reads.
        #pragma unroll
        for (int m = 0; m < 8; ++m) {
            int chunk = m * 64 + l;           // 480 16B-chunks (60 rows x 8)
            if (chunk < 480) {
                int row = chunk >> 3, c = chunk & 7;
                const float* p = xp + row * 64 + c * 8;
                half8 hv = pk8(*(const f4*)p, *(const f4*)(p + 4));
                *(half8*)&wlds[xbase + row * 64 + ((c * 8) ^ ((row & 7) << 3))] = hv;
            }
        }

        const f4 zc = {0.f, 0.f, 0.f, 0.f};
        f4 acc2[4][2];
        f4 brow[4];
        half8 qf[4][2], kf[4][2], vf[4][2], pf[4][2], wtf[4][2], h1f[4][2];

        // ---- qT = Wq * xT + bq
        #pragma unroll
        for (int mt = 0; mt < 4; ++mt) brow[mt] = *(const f4*)&bq[16 * mt + 4 * g];
        #pragma unroll
        for (int h = 0; h < 2; ++h) {
            GEMM_H(WFRAG(0, t), XFRAG(nt), brow[mt]);
            MKFR_H(qf, false);
        }

        // ---- kT = Wk * xT + bk
        #pragma unroll
        for (int mt = 0; mt < 4; ++mt) brow[mt] = *(const f4*)&bk[16 * mt + 4 * g];
        #pragma unroll
        for (int h = 0; h < 2; ++h) {
            GEMM_H(WFRAG(1, t), XFRAG(nt), brow[mt]);
            MKFR_H(kf, false);
        }

        // ---- scoresT + softmax + P, per half (A = kf regs, B = qf regs)
        #pragma unroll
        for (int h = 0; h < 2; ++h) {
            GEMM_H(kf[t][ks], qf[nt][ks], zc);
            #pragma unroll
            for (int nb = 0; nb < 2; ++nb) {
                float sum = 0.f;
                #pragma unroll
                for (int mt = 0; mt < 4; ++mt)
                    #pragma unroll
                    for (int j = 0; j < 4; ++j) {
                        float e = (mt == 3 && g == 3)
                                      ? 0.f
                                      : exp2f(acc2[mt][nb][j] *
                                              0.1803368801111137f);
                        acc2[mt][nb][j] = e;
                        sum += e;
                    }
                sum += __shfl_xor(sum, 16);
                sum += __shfl_xor(sum, 32);
                float inv = 1.f / sum;
                #pragma unroll
                for (int mt = 0; mt < 4; ++mt)
                    #pragma unroll
                    for (int j = 0; j < 4; ++j) acc2[mt][nb][j] *= inv;
            }
            MKFR_H(pf, false);
        }
        // qf, kf dead here.

        // ---- v = x * WvT + bv (col-splat C-in), per half
        #pragma unroll
        for (int h = 0; h < 2; ++h) {
            float bc[2];
            #pragma unroll
            for (int nb = 0; nb < 2; ++nb) bc[nb] = bv[16 * (2 * h + nb) + lo];
            GEMM_H(XFRAG(t), WFRAG(2, nt),
                   ((f4){bc[nb], bc[nb], bc[nb], bc[nb]}));
            MKFR_H(vf, false);
        }

        // ---- weightedT = vT * P, per half (A = vf regs, B = pf regs)
        #pragma unroll
        for (int h = 0; h < 2; ++h) {
            GEMM_H(vf[t][ks], pf[nt][ks], zc);
            MKFR_H(wtf, false);
        }
        // vf, pf dead here.

        // ---- h1T = relu(W1 * weightedT + b1)   (W1 pi-permuted)
        #pragma unroll
        for (int mt = 0; mt < 4; ++mt) brow[mt] = *(const f4*)&b1[16 * mt + 4 * g];
        #pragma unroll
        for (int h = 0; h < 2; ++h) {
            GEMM_H(WFRAG(3, t), wtf[nt][ks], brow[mt]);
            MKFR_H(h1f, true);
        }

        // ---- h2T = relu(W2 * h1T + b2), head folded per half on f32 acc
        #pragma unroll
        for (int mt = 0; mt < 4; ++mt) brow[mt] = *(const f4*)&b2[16 * mt + 4 * g];
        f4 w3r[4];
        #pragma unroll
        for (int mt = 0; mt < 4; ++mt) w3r[mt] = *(const f4*)&W3[16 * mt + 4 * g];
        float b3v = b3[0];
        #pragma unroll
        for (int h = 0; h < 2; ++h) {
            GEMM_H(WFRAG(4, t), h1f[nt][ks], brow[mt]);
            #pragma unroll
            for (int nb = 0; nb < 2; ++nb) {
                float sres = 0.f;
                #pragma unroll
                for (int mt = 0; mt < 4; ++mt)
                    #pragma unroll
                    for (int j = 0; j < 4; ++j)
                        sres += fmaxf(acc2[mt][nb][j], 0.f) * w3r[mt][j];
                sres += __shfl_xor(sres, 16);
                sres += __shfl_xor(sres, 32);
                if (g == 0) {
                    int s = 16 * (2 * h + nb) + lo;
                    if (s < 60) out[(size_t)part * 60 + s] = sres + b3v;
                }
            }
        }
    }
}

extern "C" void kernel_launch(void* const* d_in, const int* in_sizes, int n_in,
                              void* d_out, int out_size, void* d_ws, size_t ws_size,
                              hipStream_t stream) {
    const float* x  = (const float*)d_in[0];
    const float* Wq = (const float*)d_in[1];
    const float* bq = (const float*)d_in[2];
    const float* Wk = (const float*)d_in[3];
    const float* bk = (const float*)d_in[4];
    const float* Wv = (const float*)d_in[5];
    const float* bv = (const float*)d_in[6];
    const float* W1 = (const float*)d_in[7];
    const float* b1 = (const float*)d_in[8];
    const float* W2 = (const float*)d_in[9];
    const float* b2 = (const float*)d_in[10];
    const float* W3 = (const float*)d_in[11];
    const float* b3 = (const float*)d_in[12];
    _Float16* wsH = (_Float16*)d_ws;  // 5 * 4096 halves = 40 KB

    prep_weights<<<80, 256, 0, stream>>>(Wq, Wk, Wv, W1, W2, wsH);
    // 1280 WGs x 256 thr (4 waves/WG), 2 sequential parts/wave = 5120 waves.
    // 256-thr budget = 256 VGPR -> the loop cannot spill; LDS 70 KB -> 2 WGs/CU.
    fused_f16<<<1280, 256, 0, stream>>>(x, wsH, bq, bk, bv, b1, b2, W3, b3,
                                        (float*)d_out);
}

// Round 29
// 84.117 us; speedup vs baseline: 1.0031x; 1.0031x over previous
//
#include <hip/hip_runtime.h>
#include <math.h>

// B=256, P=40, S=60, D=64. Round-28 = Round-27's 2-sequential-parts plan in
// a 256-THREAD WG. Evidence chain: R26/R27 proved any part-loop at 512-thr
// spills (allocator budget 65536/512 = 128; body 112 + loop state > 128 ->
// ~20 MB scratch, the 12-16 us poison). 256-thr budget = 256: R9/R14 looped
// bodies allocated 156-240 there with ZERO spill. Config: 1280 WGs x 256 thr
// (4 waves/WG), 2 parts/wave = 5120 waves; LDS = 40 KB weights + 4 x-tiles
// = 70 KB -> 2 WGs/CU co-resident (8 waves/CU, same as R20's best) with no
// spill possible. Model: WG lifetime ~21 us, 5 WGs/CU at 2 co-resident
// -> ~52 us + ramp.
//
// Register-chain trick: MFMA contraction is invariant to permuting the k-dim.
// C/D output holds the row-dim in-lane as {16mt+4g+j}; the next GEMM
// contracting that dim takes both operands by pure register reindexing:
//     frag[nt][ks] = pk16( acc2[2ks][nb], acc2[2ks+1][nb] )
// map pi(ks,i,g)=16*(2ks+(i>>2))+4g+(i&3). W1/W2 pre-permuted to pi-layout.
//
// Layout facts (cdna4 guide, measured m89/m91):
//   C/D: lane holds col=lane&15, rows 16mt+4(lane>>4)+j
//   A/B: row(col)=lane&15, kappa = 32ks+8(lane>>4)+i

typedef _Float16 half8 __attribute__((ext_vector_type(8)));
typedef __fp16 fp16x2 __attribute__((ext_vector_type(2)));
typedef float f4 __attribute__((ext_vector_type(4)));

#define MFMA16(a, b, c) __builtin_amdgcn_mfma_f32_16x16x32_f16((a), (b), (c), 0, 0, 0)

__global__ __launch_bounds__(256) void prep_weights(
    const float* __restrict__ Wq, const float* __restrict__ Wk,
    const float* __restrict__ Wv, const float* __restrict__ W1,
    const float* __restrict__ W2, _Float16* __restrict__ wsH) {
    int idx = blockIdx.x * 256 + threadIdx.x;  // 0..20479
    int m = idx >> 12, r = idx & 4095;
    const float* src = (m == 0) ? Wq : (m == 1) ? Wk : (m == 2) ? Wv
                        : (m == 3) ? W1 : W2;
    float v;
    if (m < 3) {
        v = src[r];  // natural row-major [e][d]
    } else {
        // pi-permuted: position (e, kappa) holds W[e][ d=16*(2ks+(i>>2))+4g+(i&3) ]
        int e = r >> 6, kp = r & 63;
        int ks = kp >> 5, gg = (kp >> 3) & 3, i = kp & 7;
        int d = 16 * (2 * ks + (i >> 2)) + 4 * gg + (i & 3);
        v = src[e * 64 + d];
    }
    wsH[idx] = (_Float16)v;
}

// Packed f32x4 + f32x4 -> half8 via v_cvt_pkrtz_f16_f32 (4 insts).
__device__ __forceinline__ half8 pk8(f4 a, f4 b) {
    union { half8 h; fp16x2 p[4]; } u;
    u.p[0] = __builtin_amdgcn_cvt_pkrtz(a[0], a[1]);
    u.p[1] = __builtin_amdgcn_cvt_pkrtz(a[2], a[3]);
    u.p[2] = __builtin_amdgcn_cvt_pkrtz(b[0], b[1]);
    u.p[3] = __builtin_amdgcn_cvt_pkrtz(b[2], b[3]);
    return u.h;
}

// Half-width GEMM into acc2[4][2]: output cols nt in {2h, 2h+1}.
// AEXPR uses (t, ks); BEXPR uses (nt, ks); CEXPR uses (mt, nb, nt).
#define GEMM_H(AEXPR, BEXPR, CEXPR)                                          \
    do {                                                                     \
        _Pragma("unroll")                                                    \
        for (int ks = 0; ks < 2; ++ks) {                                     \
            half8 afr[4], bfr[2];                                            \
            _Pragma("unroll")                                                \
            for (int t = 0; t < 4; ++t) afr[t] = (AEXPR);                    \
            _Pragma("unroll")                                                \
            for (int nb = 0; nb < 2; ++nb) {                                 \
                const int nt = 2 * h + nb; (void)nt;                         \
                bfr[nb] = (BEXPR);                                           \
            }                                                                \
            _Pragma("unroll")                                                \
            for (int mt = 0; mt < 4; ++mt)                                   \
                _Pragma("unroll")                                            \
                for (int nb = 0; nb < 2; ++nb) {                             \
                    const int nt = 2 * h + nb; (void)nt;                     \
                    acc2[mt][nb] = MFMA16(afr[mt], bfr[nb],                  \
                                          ks == 0 ? (CEXPR) : acc2[mt][nb]); \
                }                                                            \
        }                                                                    \
    } while (0)

// acc2 -> pi-layout frags for this half (dst[2h+nb][ks]).
#define MKFR_H(dst, RELU)                                                    \
    do {                                                                     \
        _Pragma("unroll")                                                    \
        for (int nb = 0; nb < 2; ++nb)                                       \
            _Pragma("unroll")                                                \
            for (int ks = 0; ks < 2; ++ks) {                                 \
                f4 a_ = acc2[2 * ks][nb], b_ = acc2[2 * ks + 1][nb];         \
                if (RELU) {                                                  \
                    _Pragma("unroll")                                        \
                    for (int j = 0; j < 4; ++j) {                            \
                        a_[j] = fmaxf(a_[j], 0.f);                           \
                        b_[j] = fmaxf(b_[j], 0.f);                           \
                    }                                                        \
                }                                                            \
                dst[2 * h + nb][ks] = pk8(a_, b_);                           \
            }                                                                \
    } while (0)

// Weight fragment from LDS: matrix widx, row-block RB (row = 16*RB+lo),
// kappa chunk (32ks+8g), XOR-swizzled by (lo&7)<<3 halves.
#define WFRAG(widx, RB) (*(const half8*)&wlds[(widx) * 4096 + (16 * (RB) + lo) * 64 + \
                                              ((32 * ks + 8 * g) ^ ((lo & 7) << 3))])

// x fragment from LDS (rows >= 60 -> zero; constant-folds for RB < 3).
#define XFRAG(RB) __extension__({                                            \
    int row_ = 16 * (RB) + lo;                                               \
    int rowc_ = row_ < 60 ? row_ : 48;                                       \
    half8 v_ = *(const half8*)&wlds[xbase + rowc_ * 64 +                     \
                                    ((32 * ks + 8 * g) ^ ((lo & 7) << 3))];  \
    if (row_ >= 60) { half8 z_ = {}; v_ = z_; }                              \
    v_; })

__global__ __launch_bounds__(256, 1) void fused_f16(
    const float* __restrict__ x, const _Float16* __restrict__ wH,
    const float* __restrict__ bq, const float* __restrict__ bk,
    const float* __restrict__ bv, const float* __restrict__ b1,
    const float* __restrict__ b2, const float* __restrict__ W3,
    const float* __restrict__ b3, float* __restrict__ out) {
    // 40 KB weights + 4 x-tiles (60x64 f16, swizzled) = 71680 B = 70 KB.
    __shared__ __align__(16) _Float16 wlds[35840];

    const int tid = threadIdx.x;
    const int l = tid & 63;           // lane
    const int w = tid >> 6;           // wave 0..3 (TWO sequential parts each)
    const int lo = l & 15, g = l >> 4;

    // ---- cooperative weight load global->LDS with write-side swizzle.
    #pragma unroll
    for (int rep = 0; rep < 10; ++rep) {
        int chunk = rep * 256 + tid;          // 0..2559
        int widx = chunk >> 9;
        int rem = chunk & 511;
        int row = rem >> 3, c = rem & 7;
        *(half8*)&wlds[widx * 4096 + row * 64 + ((c * 8) ^ ((row & 7) << 3))] =
            *(const half8*)&wH[widx * 4096 + row * 64 + c * 8];
    }
    __syncthreads();  // weights visible to all; waves independent afterwards

    const int part0 = blockIdx.x * 8 + w * 2;   // two consecutive parts
    const int xbase = 20480 + w * 3840;         // x tile reused per iteration

    #pragma unroll 1
    for (int it = 0; it < 2; ++it) {
        // Pin the back-edge: iteration it+1's loads may not hoist into it.
        __builtin_amdgcn_sched_barrier(0);

        const int part = part0 + it;
        const float* __restrict__ xp = x + (size_t)part * (60 * 64);

        // ---- stage this part's x into LDS (f16, swizzled). Same-wave
        // in-order LDS: this iteration's writes follow prior reads.
        #pragma unroll
        for (int m = 0; m < 8; ++m) {
            int chunk = m * 64 + l;           // 480 16B-chunks (60 rows x 8)
            if (chunk < 480) {
                int row = chunk >> 3, c = chunk & 7;
                const float* p = xp + row * 64 + c * 8;
                half8 hv = pk8(*(const f4*)p, *(const f4*)(p + 4));
                *(half8*)&wlds[xbase + row * 64 + ((c * 8) ^ ((row & 7) << 3))] = hv;
            }
        }

        const f4 zc = {0.f, 0.f, 0.f, 0.f};
        f4 acc2[4][2];
        f4 brow[4];
        half8 qf[4][2], kf[4][2], vf[4][2], pf[4][2], wtf[4][2], h1f[4][2];

        // ---- qT = Wq * xT + bq
        #pragma unroll
        for (int mt = 0; mt < 4; ++mt) brow[mt] = *(const f4*)&bq[16 * mt + 4 * g];
        #pragma unroll
        for (int h = 0; h < 2; ++h) {
            GEMM_H(WFRAG(0, t), XFRAG(nt), brow[mt]);
            MKFR_H(qf, false);
        }

        // ---- kT = Wk * xT + bk
        #pragma unroll
        for (int mt = 0; mt < 4; ++mt) brow[mt] = *(const f4*)&bk[16 * mt + 4 * g];
        #pragma unroll
        for (int h = 0; h < 2; ++h) {
            GEMM_H(WFRAG(1, t), XFRAG(nt), brow[mt]);
            MKFR_H(kf, false);
        }

        // ---- scoresT + softmax + P, per half (A = kf regs, B = qf regs)
        #pragma unroll
        for (int h = 0; h < 2; ++h) {
            GEMM_H(kf[t][ks], qf[nt][ks], zc);
            #pragma unroll
            for (int nb = 0; nb < 2; ++nb) {
                float sum = 0.f;
                #pragma unroll
                for (int mt = 0; mt < 4; ++mt)
                    #pragma unroll
                    for (int j = 0; j < 4; ++j) {
                        float e = (mt == 3 && g == 3)
                                      ? 0.f
                                      : exp2f(acc2[mt][nb][j] *
                                              0.1803368801111137f);
                        acc2[mt][nb][j] = e;
                        sum += e;
                    }
                sum += __shfl_xor(sum, 16);
                sum += __shfl_xor(sum, 32);
                float inv = 1.f / sum;
                #pragma unroll
                for (int mt = 0; mt < 4; ++mt)
                    #pragma unroll
                    for (int j = 0; j < 4; ++j) acc2[mt][nb][j] *= inv;
            }
            MKFR_H(pf, false);
        }
        // qf, kf dead here.

        // ---- v = x * WvT + bv (col-splat C-in), per half
        #pragma unroll
        for (int h = 0; h < 2; ++h) {
            float bc[2];
            #pragma unroll
            for (int nb = 0; nb < 2; ++nb) bc[nb] = bv[16 * (2 * h + nb) + lo];
            GEMM_H(XFRAG(t), WFRAG(2, nt),
                   ((f4){bc[nb], bc[nb], bc[nb], bc[nb]}));
            MKFR_H(vf, false);
        }

        // ---- weightedT = vT * P, per half (A = vf regs, B = pf regs)
        #pragma unroll
        for (int h = 0; h < 2; ++h) {
            GEMM_H(vf[t][ks], pf[nt][ks], zc);
            MKFR_H(wtf, false);
        }
        // vf, pf dead here.

        // ---- h1T = relu(W1 * weightedT + b1)   (W1 pi-permuted)
        #pragma unroll
        for (int mt = 0; mt < 4; ++mt) brow[mt] = *(const f4*)&b1[16 * mt + 4 * g];
        #pragma unroll
        for (int h = 0; h < 2; ++h) {
            GEMM_H(WFRAG(3, t), wtf[nt][ks], brow[mt]);
            MKFR_H(h1f, true);
        }

        // ---- h2T = relu(W2 * h1T + b2), head folded per half on f32 acc
        #pragma unroll
        for (int mt = 0; mt < 4; ++mt) brow[mt] = *(const f4*)&b2[16 * mt + 4 * g];
        f4 w3r[4];
        #pragma unroll
        for (int mt = 0; mt < 4; ++mt) w3r[mt] = *(const f4*)&W3[16 * mt + 4 * g];
        float b3v = b3[0];
        #pragma unroll
        for (int h = 0; h < 2; ++h) {
            GEMM_H(WFRAG(4, t), h1f[nt][ks], brow[mt]);
            #pragma unroll
            for (int nb = 0; nb < 2; ++nb) {
                float sres = 0.f;
                #pragma unroll
                for (int mt = 0; mt < 4; ++mt)
                    #pragma unroll
                    for (int j = 0; j < 4; ++j)
                        sres += fmaxf(acc2[mt][nb][j], 0.f) * w3r[mt][j];
                sres += __shfl_xor(sres, 16);
                sres += __shfl_xor(sres, 32);
                if (g == 0) {
                    int s = 16 * (2 * h + nb) + lo;
                    if (s < 60) out[(size_t)part * 60 + s] = sres + b3v;
                }
            }
        }
    }
}

extern "C" void kernel_launch(void* const* d_in, const int* in_sizes, int n_in,
                              void* d_out, int out_size, void* d_ws, size_t ws_size,
                              hipStream_t stream) {
    const float* x  = (const float*)d_in[0];
    const float* Wq = (const float*)d_in[1];
    const float* bq = (const float*)d_in[2];
    const float* Wk = (const float*)d_in[3];
    const float* bk = (const float*)d_in[4];
    const float* Wv = (const float*)d_in[5];
    const float* bv = (const float*)d_in[6];
    const float* W1 = (const float*)d_in[7];
    const float* b1 = (const float*)d_in[8];
    const float* W2 = (const float*)d_in[9];
    const float* b2 = (const float*)d_in[10];
    const float* W3 = (const float*)d_in[11];
    const float* b3 = (const float*)d_in[12];
    _Float16* wsH = (_Float16*)d_ws;  // 5 * 4096 halves = 40 KB

    prep_weights<<<80, 256, 0, stream>>>(Wq, Wk, Wv, W1, W2, wsH);
    // 1280 WGs x 256 thr (4 waves/WG), 2 sequential parts/wave = 5120 waves.
    // 256-thr budget = 256 VGPR -> the loop cannot spill; LDS 70 KB -> 2 WGs/CU.
    fused_f16<<<1280, 256, 0, stream>>>(x, wsH, bq, bk, bv, b1, b2, W3, b3,
                                        (float*)d_out);
}

// Round 30
// 75.558 us; speedup vs baseline: 1.1167x; 1.1133x over previous
//
#include <hip/hip_runtime.h>
#include <math.h>

// B=256, P=40, S=60, D=64. Round-30: 2 parts per wave as STRAIGHT-LINE code
// (no loop). Evidence: 512-thr + part-LOOP spills (R26/R27: body 112 + loop
// state > 128 budget -> ~20 MB scratch); 256-thr loop doesn't spill but gets
// only ~3.4 waves/CU (R28/29). Here: two fence-separated scoped blocks, all
// fragments block-scoped so liveness never crosses the sched_barrier(0) seam
// -> allocator should land ~116 like R25. Discriminating experiment: if
// R20/R25 (69.5 us) were wave-dispatch-limited (147 waves/us), 5120 waves
// -> 45-60 us; if residency x chain limited, ~70-85 and the basin is final.
//
// Register-chain trick: MFMA contraction is invariant to permuting the k-dim.
// C/D output holds the row-dim in-lane as {16mt+4g+j}; the next GEMM
// contracting that dim takes both operands by pure register reindexing:
//     frag[nt][ks] = pk16( acc2[2ks][nb], acc2[2ks+1][nb] )
// map pi(ks,i,g)=16*(2ks+(i>>2))+4g+(i&3). W1/W2 pre-permuted to pi-layout.
//
// Layout facts (cdna4 guide, measured m89/m91):
//   C/D: lane holds col=lane&15, rows 16mt+4(lane>>4)+j
//   A/B: row(col)=lane&15, kappa = 32ks+8(lane>>4)+i

typedef _Float16 half8 __attribute__((ext_vector_type(8)));
typedef __fp16 fp16x2 __attribute__((ext_vector_type(2)));
typedef float f4 __attribute__((ext_vector_type(4)));

#define MFMA16(a, b, c) __builtin_amdgcn_mfma_f32_16x16x32_f16((a), (b), (c), 0, 0, 0)

__global__ __launch_bounds__(256) void prep_weights(
    const float* __restrict__ Wq, const float* __restrict__ Wk,
    const float* __restrict__ Wv, const float* __restrict__ W1,
    const float* __restrict__ W2, _Float16* __restrict__ wsH) {
    int idx = blockIdx.x * 256 + threadIdx.x;  // 0..20479
    int m = idx >> 12, r = idx & 4095;
    const float* src = (m == 0) ? Wq : (m == 1) ? Wk : (m == 2) ? Wv
                        : (m == 3) ? W1 : W2;
    float v;
    if (m < 3) {
        v = src[r];  // natural row-major [e][d]
    } else {
        // pi-permuted: position (e, kappa) holds W[e][ d=16*(2ks+(i>>2))+4g+(i&3) ]
        int e = r >> 6, kp = r & 63;
        int ks = kp >> 5, gg = (kp >> 3) & 3, i = kp & 7;
        int d = 16 * (2 * ks + (i >> 2)) + 4 * gg + (i & 3);
        v = src[e * 64 + d];
    }
    wsH[idx] = (_Float16)v;
}

// Packed f32x4 + f32x4 -> half8 via v_cvt_pkrtz_f16_f32 (4 insts).
__device__ __forceinline__ half8 pk8(f4 a, f4 b) {
    union { half8 h; fp16x2 p[4]; } u;
    u.p[0] = __builtin_amdgcn_cvt_pkrtz(a[0], a[1]);
    u.p[1] = __builtin_amdgcn_cvt_pkrtz(a[2], a[3]);
    u.p[2] = __builtin_amdgcn_cvt_pkrtz(b[0], b[1]);
    u.p[3] = __builtin_amdgcn_cvt_pkrtz(b[2], b[3]);
    return u.h;
}

// Half-width GEMM into acc2[4][2]: output cols nt in {2h, 2h+1}.
#define GEMM_H(AEXPR, BEXPR, CEXPR)                                          \
    do {                                                                     \
        _Pragma("unroll")                                                    \
        for (int ks = 0; ks < 2; ++ks) {                                     \
            half8 afr[4], bfr[2];                                            \
            _Pragma("unroll")                                                \
            for (int t = 0; t < 4; ++t) afr[t] = (AEXPR);                    \
            _Pragma("unroll")                                                \
            for (int nb = 0; nb < 2; ++nb) {                                 \
                const int nt = 2 * h + nb; (void)nt;                         \
                bfr[nb] = (BEXPR);                                           \
            }                                                                \
            _Pragma("unroll")                                                \
            for (int mt = 0; mt < 4; ++mt)                                   \
                _Pragma("unroll")                                            \
                for (int nb = 0; nb < 2; ++nb) {                             \
                    const int nt = 2 * h + nb; (void)nt;                     \
                    acc2[mt][nb] = MFMA16(afr[mt], bfr[nb],                  \
                                          ks == 0 ? (CEXPR) : acc2[mt][nb]); \
                }                                                            \
        }                                                                    \
    } while (0)

// acc2 -> pi-layout frags for this half (dst[2h+nb][ks]).
#define MKFR_H(dst, RELU)                                                    \
    do {                                                                     \
        _Pragma("unroll")                                                    \
        for (int nb = 0; nb < 2; ++nb)                                       \
            _Pragma("unroll")                                                \
            for (int ks = 0; ks < 2; ++ks) {                                 \
                f4 a_ = acc2[2 * ks][nb], b_ = acc2[2 * ks + 1][nb];         \
                if (RELU) {                                                  \
                    _Pragma("unroll")                                        \
                    for (int j = 0; j < 4; ++j) {                            \
                        a_[j] = fmaxf(a_[j], 0.f);                           \
                        b_[j] = fmaxf(b_[j], 0.f);                           \
                    }                                                        \
                }                                                            \
                dst[2 * h + nb][ks] = pk8(a_, b_);                           \
            }                                                                \
    } while (0)

// Weight fragment from LDS (XOR-swizzled); x fragment from this wave's tile.
#define WFRAG(widx, RB) (*(const half8*)&wlds[(widx) * 4096 + (16 * (RB) + lo) * 64 + \
                                              ((32 * ks + 8 * g) ^ ((lo & 7) << 3))])
#define XFRAG(RB) __extension__({                                            \
    int row_ = 16 * (RB) + lo;                                               \
    int rowc_ = row_ < 60 ? row_ : 48;                                       \
    half8 v_ = *(const half8*)&wlds[xbase + rowc_ * 64 +                     \
                                    ((32 * ks + 8 * g) ^ ((lo & 7) << 3))];  \
    if (row_ >= 60) { half8 z_ = {}; v_ = z_; }                              \
    v_; })

// One full part, all state block-scoped (liveness cannot cross the seam).
#define PART_BODY(PART)                                                      \
    {                                                                        \
        const int part = (PART);                                             \
        const float* __restrict__ xp = x + (size_t)part * (60 * 64);         \
        _Pragma("unroll")                                                    \
        for (int m = 0; m < 8; ++m) {                                        \
            int chunk = m * 64 + l;                                          \
            if (chunk < 480) {                                               \
                int row = chunk >> 3, c = chunk & 7;                         \
                const float* p = xp + row * 64 + c * 8;                      \
                half8 hv = pk8(*(const f4*)p, *(const f4*)(p + 4));          \
                *(half8*)&wlds[xbase + row * 64 +                            \
                               ((c * 8) ^ ((row & 7) << 3))] = hv;           \
            }                                                                \
        }                                                                    \
        const f4 zc = {0.f, 0.f, 0.f, 0.f};                                  \
        f4 acc2[4][2];                                                       \
        f4 brow[4];                                                          \
        half8 qf[4][2], kf[4][2], vf[4][2], pf[4][2], wtf[4][2], h1f[4][2];  \
        _Pragma("unroll")                                                    \
        for (int mt = 0; mt < 4; ++mt)                                       \
            brow[mt] = *(const f4*)&bq[16 * mt + 4 * g];                     \
        _Pragma("unroll")                                                    \
        for (int h = 0; h < 2; ++h) {                                        \
            GEMM_H(WFRAG(0, t), XFRAG(nt), brow[mt]);                        \
            MKFR_H(qf, false);                                               \
        }                                                                    \
        _Pragma("unroll")                                                    \
        for (int mt = 0; mt < 4; ++mt)                                       \
            brow[mt] = *(const f4*)&bk[16 * mt + 4 * g];                     \
        _Pragma("unroll")                                                    \
        for (int h = 0; h < 2; ++h) {                                        \
            GEMM_H(WFRAG(1, t), XFRAG(nt), brow[mt]);                        \
            MKFR_H(kf, false);                                               \
        }                                                                    \
        _Pragma("unroll")                                                    \
        for (int h = 0; h < 2; ++h) {                                        \
            GEMM_H(kf[t][ks], qf[nt][ks], zc);                               \
            _Pragma("unroll")                                                \
            for (int nb = 0; nb < 2; ++nb) {                                 \
                float sum = 0.f;                                             \
                _Pragma("unroll")                                            \
                for (int mt = 0; mt < 4; ++mt)                               \
                    _Pragma("unroll")                                        \
                    for (int j = 0; j < 4; ++j) {                            \
                        float e = (mt == 3 && g == 3)                        \
                                      ? 0.f                                  \
                                      : exp2f(acc2[mt][nb][j] *              \
                                              0.1803368801111137f);          \
                        acc2[mt][nb][j] = e;                                 \
                        sum += e;                                            \
                    }                                                        \
                sum += __shfl_xor(sum, 16);                                  \
                sum += __shfl_xor(sum, 32);                                  \
                float inv = 1.f / sum;                                       \
                _Pragma("unroll")                                            \
                for (int mt = 0; mt < 4; ++mt)                               \
                    _Pragma("unroll")                                        \
                    for (int j = 0; j < 4; ++j) acc2[mt][nb][j] *= inv;      \
            }                                                                \
            MKFR_H(pf, false);                                               \
        }                                                                    \
        _Pragma("unroll")                                                    \
        for (int h = 0; h < 2; ++h) {                                        \
            float bc[2];                                                     \
            _Pragma("unroll")                                                \
            for (int nb = 0; nb < 2; ++nb)                                   \
                bc[nb] = bv[16 * (2 * h + nb) + lo];                         \
            GEMM_H(XFRAG(t), WFRAG(2, nt),                                   \
                   ((f4){bc[nb], bc[nb], bc[nb], bc[nb]}));                  \
            MKFR_H(vf, false);                                               \
        }                                                                    \
        _Pragma("unroll")                                                    \
        for (int h = 0; h < 2; ++h) {                                        \
            GEMM_H(vf[t][ks], pf[nt][ks], zc);                               \
            MKFR_H(wtf, false);                                              \
        }                                                                    \
        _Pragma("unroll")                                                    \
        for (int mt = 0; mt < 4; ++mt)                                       \
            brow[mt] = *(const f4*)&b1[16 * mt + 4 * g];                     \
        _Pragma("unroll")                                                    \
        for (int h = 0; h < 2; ++h) {                                        \
            GEMM_H(WFRAG(3, t), wtf[nt][ks], brow[mt]);                      \
            MKFR_H(h1f, true);                                               \
        }                                                                    \
        _Pragma("unroll")                                                    \
        for (int mt = 0; mt < 4; ++mt)                                       \
            brow[mt] = *(const f4*)&b2[16 * mt + 4 * g];                     \
        f4 w3r[4];                                                           \
        _Pragma("unroll")                                                    \
        for (int mt = 0; mt < 4; ++mt)                                       \
            w3r[mt] = *(const f4*)&W3[16 * mt + 4 * g];                      \
        float b3v = b3[0];                                                   \
        _Pragma("unroll")                                                    \
        for (int h = 0; h < 2; ++h) {                                        \
            GEMM_H(WFRAG(4, t), h1f[nt][ks], brow[mt]);                      \
            _Pragma("unroll")                                                \
            for (int nb = 0; nb < 2; ++nb) {                                 \
                float sres = 0.f;                                            \
                _Pragma("unroll")                                            \
                for (int mt = 0; mt < 4; ++mt)                               \
                    _Pragma("unroll")                                        \
                    for (int j = 0; j < 4; ++j)                              \
                        sres += fmaxf(acc2[mt][nb][j], 0.f) * w3r[mt][j];    \
                sres += __shfl_xor(sres, 16);                                \
                sres += __shfl_xor(sres, 32);                                \
                if (g == 0) {                                                \
                    int s = 16 * (2 * h + nb) + lo;                          \
                    if (s < 60) out[(size_t)part * 60 + s] = sres + b3v;     \
                }                                                            \
            }                                                                \
        }                                                                    \
    }

__global__ __launch_bounds__(512, 1) void fused_f16(
    const float* __restrict__ x, const _Float16* __restrict__ wH,
    const float* __restrict__ bq, const float* __restrict__ bk,
    const float* __restrict__ bv, const float* __restrict__ b1,
    const float* __restrict__ b2, const float* __restrict__ W3,
    const float* __restrict__ b3, float* __restrict__ out) {
    // 40 KB weights + 8 x-tiles (60x64 f16, swizzled) = 102400 B = 100 KB.
    __shared__ __align__(16) _Float16 wlds[51200];

    const int tid = threadIdx.x;
    const int l = tid & 63;           // lane
    const int w = tid >> 6;           // wave 0..7 (two straight-line parts)
    const int lo = l & 15, g = l >> 4;

    // ---- cooperative weight load global->LDS with write-side swizzle.
    #pragma unroll
    for (int rep = 0; rep < 5; ++rep) {
        int chunk = rep * 512 + tid;          // 0..2559
        int widx = chunk >> 9;
        int rem = chunk & 511;
        int row = rem >> 3, c = rem & 7;
        *(half8*)&wlds[widx * 4096 + row * 64 + ((c * 8) ^ ((row & 7) << 3))] =
            *(const half8*)&wH[widx * 4096 + row * 64 + c * 8];
    }
    __syncthreads();  // weights visible to all; waves independent afterwards

    const int part0 = blockIdx.x * 16 + w * 2;  // two consecutive parts
    const int xbase = 20480 + w * 3840;         // x tile reused by both bodies

    PART_BODY(part0)
    // Seam: no register liveness crosses (all frags block-scoped above);
    // fence blocks instruction motion between the two bodies.
    __builtin_amdgcn_sched_barrier(0);
    PART_BODY(part0 + 1)
}

extern "C" void kernel_launch(void* const* d_in, const int* in_sizes, int n_in,
                              void* d_out, int out_size, void* d_ws, size_t ws_size,
                              hipStream_t stream) {
    const float* x  = (const float*)d_in[0];
    const float* Wq = (const float*)d_in[1];
    const float* bq = (const float*)d_in[2];
    const float* Wk = (const float*)d_in[3];
    const float* bk = (const float*)d_in[4];
    const float* Wv = (const float*)d_in[5];
    const float* bv = (const float*)d_in[6];
    const float* W1 = (const float*)d_in[7];
    const float* b1 = (const float*)d_in[8];
    const float* W2 = (const float*)d_in[9];
    const float* b2 = (const float*)d_in[10];
    const float* W3 = (const float*)d_in[11];
    const float* b3 = (const float*)d_in[12];
    _Float16* wsH = (_Float16*)d_ws;  // 5 * 4096 halves = 40 KB

    prep_weights<<<80, 256, 0, stream>>>(Wq, Wk, Wv, W1, W2, wsH);
    // 640 WGs x 512 thr = 5120 waves; 2 straight-line parts per wave
    // (no loop state -> no spill; fence-separated bodies).
    fused_f16<<<640, 512, 0, stream>>>(x, wsH, bq, bk, bv, b1, b2, W3, b3,
                                       (float*)d_out);
}

// Round 31
// 69.303 us; speedup vs baseline: 1.2175x; 1.0903x over previous
//
#include <hip/hip_runtime.h>
#include <math.h>

// B=256, P=40, S=60, D=64. FINAL (champion, R25 = session best 69.5 us).
// One part per wave; 1280 WGs x 512 thr; weights (pi-permuted, f16) +
// per-wave x tiles in LDS (100 KB, XOR-swizzled, conflict-free b128 reads);
// half-width GEMMs (acc2[4][2]) keep liveness at 116 VGPR (no spill);
// bias folded into the MFMA C operand; softmax without max-subtraction
// (scores ~N(0,1)); f32->f16 via packed cvt_pkrtz; zero-shuffle register
// chain between all 7 GEMMs. Configuration space mapped R20-R30: all
// multi-part / larger-WG / cooperative variants are blocked by measured
// allocator budget (65536/threads) or scheduler residency (~6.5 waves/CU).
//
// Register-chain trick: MFMA contraction is invariant to permuting the k-dim.
// C/D output holds the row-dim in-lane as {16mt+4g+j}; the next GEMM
// contracting that dim takes both operands by pure register reindexing:
//     frag[nt][ks] = pk16( acc2[2ks][nb], acc2[2ks+1][nb] )
// map pi(ks,i,g)=16*(2ks+(i>>2))+4g+(i&3). W1/W2 pre-permuted to pi-layout.
//
// Layout facts (cdna4 guide, measured m89/m91):
//   C/D: lane holds col=lane&15, rows 16mt+4(lane>>4)+j
//   A/B: row(col)=lane&15, kappa = 32ks+8(lane>>4)+i

typedef _Float16 half8 __attribute__((ext_vector_type(8)));
typedef __fp16 fp16x2 __attribute__((ext_vector_type(2)));
typedef float f4 __attribute__((ext_vector_type(4)));

#define MFMA16(a, b, c) __builtin_amdgcn_mfma_f32_16x16x32_f16((a), (b), (c), 0, 0, 0)

__global__ __launch_bounds__(256) void prep_weights(
    const float* __restrict__ Wq, const float* __restrict__ Wk,
    const float* __restrict__ Wv, const float* __restrict__ W1,
    const float* __restrict__ W2, _Float16* __restrict__ wsH) {
    int idx = blockIdx.x * 256 + threadIdx.x;  // 0..20479
    int m = idx >> 12, r = idx & 4095;
    const float* src = (m == 0) ? Wq : (m == 1) ? Wk : (m == 2) ? Wv
                        : (m == 3) ? W1 : W2;
    float v;
    if (m < 3) {
        v = src[r];  // natural row-major [e][d]
    } else {
        // pi-permuted: position (e, kappa) holds W[e][ d=16*(2ks+(i>>2))+4g+(i&3) ]
        int e = r >> 6, kp = r & 63;
        int ks = kp >> 5, gg = (kp >> 3) & 3, i = kp & 7;
        int d = 16 * (2 * ks + (i >> 2)) + 4 * gg + (i & 3);
        v = src[e * 64 + d];
    }
    wsH[idx] = (_Float16)v;
}

// Packed f32x4 + f32x4 -> half8 via v_cvt_pkrtz_f16_f32 (4 insts).
__device__ __forceinline__ half8 pk8(f4 a, f4 b) {
    union { half8 h; fp16x2 p[4]; } u;
    u.p[0] = __builtin_amdgcn_cvt_pkrtz(a[0], a[1]);
    u.p[1] = __builtin_amdgcn_cvt_pkrtz(a[2], a[3]);
    u.p[2] = __builtin_amdgcn_cvt_pkrtz(b[0], b[1]);
    u.p[3] = __builtin_amdgcn_cvt_pkrtz(b[2], b[3]);
    return u.h;
}

// acc2 -> pi-layout frags for this half (dst[2h+nb][ks]).
#define MKFR_H(dst, RELU)                                                    \
    do {                                                                     \
        _Pragma("unroll")                                                    \
        for (int nb = 0; nb < 2; ++nb)                                       \
            _Pragma("unroll")                                                \
            for (int ks = 0; ks < 2; ++ks) {                                 \
                f4 a_ = acc2[2 * ks][nb], b_ = acc2[2 * ks + 1][nb];         \
                if (RELU) {                                                  \
                    _Pragma("unroll")                                        \
                    for (int j = 0; j < 4; ++j) {                            \
                        a_[j] = fmaxf(a_[j], 0.f);                           \
                        b_[j] = fmaxf(b_[j], 0.f);                           \
                    }                                                        \
                }                                                            \
                dst[2 * h + nb][ks] = pk8(a_, b_);                           \
            }                                                                \
    } while (0)

// Half-width GEMM into acc2[4][2] with A already in regs (AREG indexed
// [mt][ks]); B loaded per (h, ks). Used for scores/PV (A = kf/vf).
#define GEMM_R(AREG, BEXPR, CEXPR)                                           \
    do {                                                                     \
        _Pragma("unroll")                                                    \
        for (int ks = 0; ks < 2; ++ks) {                                     \
            half8 bfr[2];                                                    \
            _Pragma("unroll")                                                \
            for (int nb = 0; nb < 2; ++nb) {                                 \
                const int nt = 2 * h + nb; (void)nt;                         \
                bfr[nb] = (BEXPR);                                           \
            }                                                                \
            _Pragma("unroll")                                                \
            for (int mt = 0; mt < 4; ++mt)                                   \
                _Pragma("unroll")                                            \
                for (int nb = 0; nb < 2; ++nb) {                             \
                    const int nt = 2 * h + nb; (void)nt;                     \
                    acc2[mt][nb] = MFMA16(AREG[mt][ks], bfr[nb],             \
                                          ks == 0 ? (CEXPR) : acc2[mt][nb]); \
                }                                                            \
        }                                                                    \
    } while (0)

// Full stage with A-frag preload shared across BOTH halves.
// AEXPR uses (t, ks); BEXPR uses (nt, ks); CEXPR uses (mt, nb, nt).
#define STAGE_A(AEXPR, BEXPR, CEXPR, DST, RELU)                              \
    do {                                                                     \
        half8 afr2[4][2];                                                    \
        _Pragma("unroll")                                                    \
        for (int t = 0; t < 4; ++t)                                          \
            _Pragma("unroll")                                                \
            for (int ks = 0; ks < 2; ++ks) afr2[t][ks] = (AEXPR);            \
        _Pragma("unroll")                                                    \
        for (int h = 0; h < 2; ++h) {                                        \
            GEMM_R(afr2, BEXPR, CEXPR);                                      \
            MKFR_H(DST, RELU);                                               \
        }                                                                    \
    } while (0)

// Weight fragment from LDS: matrix widx, row-block RB (row = 16*RB+lo),
// kappa chunk (32ks+8g), XOR-swizzled by (lo&7)<<3 halves.
#define WFRAG(widx, RB) (*(const half8*)&wlds[(widx) * 4096 + (16 * (RB) + lo) * 64 + \
                                              ((32 * ks + 8 * g) ^ ((lo & 7) << 3))])

// x fragment from LDS (rows >= 60 -> zero; constant-folds for RB < 3).
#define XFRAG(RB) __extension__({                                            \
    int row_ = 16 * (RB) + lo;                                               \
    int rowc_ = row_ < 60 ? row_ : 48;                                       \
    half8 v_ = *(const half8*)&wlds[xbase + rowc_ * 64 +                     \
                                    ((32 * ks + 8 * g) ^ ((lo & 7) << 3))];  \
    if (row_ >= 60) { half8 z_ = {}; v_ = z_; }                              \
    v_; })

__global__ __launch_bounds__(512, 1) void fused_f16(
    const float* __restrict__ x, const _Float16* __restrict__ wH,
    const float* __restrict__ bq, const float* __restrict__ bk,
    const float* __restrict__ bv, const float* __restrict__ b1,
    const float* __restrict__ b2, const float* __restrict__ W3,
    const float* __restrict__ b3, float* __restrict__ out) {
    // 40 KB weights + 8 x-tiles (60x64 f16, swizzled) = 102400 B = 100 KB.
    __shared__ __align__(16) _Float16 wlds[51200];

    const int tid = threadIdx.x;
    const int l = tid & 63;           // lane
    const int w = tid >> 6;           // wave 0..7 (one part each)
    const int lo = l & 15, g = l >> 4;

    // ---- cooperative weight load global->LDS with write-side swizzle.
    #pragma unroll
    for (int rep = 0; rep < 5; ++rep) {
        int chunk = rep * 512 + tid;          // 0..2559
        int widx = chunk >> 9;
        int rem = chunk & 511;
        int row = rem >> 3, c = rem & 7;
        *(half8*)&wlds[widx * 4096 + row * 64 + ((c * 8) ^ ((row & 7) << 3))] =
            *(const half8*)&wH[widx * 4096 + row * 64 + c * 8];
    }
    __syncthreads();  // weights visible to all; waves independent afterwards

    const int part = blockIdx.x * 8 + w;   // one part per wave
    const int xbase = 20480 + w * 3840;    // this wave's x tile (halves)
    const float* __restrict__ xp = x + (size_t)part * (60 * 64);

    // ---- stage this part's x into LDS (f16, swizzled). Own region, same-wave
    // in-order LDS -> no barrier needed.
    #pragma unroll
    for (int m = 0; m < 8; ++m) {
        int chunk = m * 64 + l;               // 480 16B-chunks (60 rows x 8)
        if (chunk < 480) {
            int row = chunk >> 3, c = chunk & 7;
            const float* p = xp + row * 64 + c * 8;
            half8 hv = pk8(*(const f4*)p, *(const f4*)(p + 4));
            *(half8*)&wlds[xbase + row * 64 + ((c * 8) ^ ((row & 7) << 3))] = hv;
        }
    }

    const f4 zc = {0.f, 0.f, 0.f, 0.f};
    f4 acc2[4][2];
    f4 brow[4];
    half8 qf[4][2], kf[4][2], vf[4][2], pf[4][2], wtf[4][2], h1f[4][2];

    // ---- qT = Wq * xT + bq   (A = Wq preloaded, shared across halves)
    #pragma unroll
    for (int mt = 0; mt < 4; ++mt) brow[mt] = *(const f4*)&bq[16 * mt + 4 * g];
    STAGE_A(WFRAG(0, t), XFRAG(nt), brow[mt], qf, false);

    // ---- kT = Wk * xT + bk
    #pragma unroll
    for (int mt = 0; mt < 4; ++mt) brow[mt] = *(const f4*)&bk[16 * mt + 4 * g];
    STAGE_A(WFRAG(1, t), XFRAG(nt), brow[mt], kf, false);

    // ---- scoresT + softmax + P, per half (A = kf regs, B = qf regs)
    #pragma unroll
    for (int h = 0; h < 2; ++h) {
        GEMM_R(kf, qf[nt][ks], zc);
        #pragma unroll
        for (int nb = 0; nb < 2; ++nb) {
            float sum = 0.f;
            #pragma unroll
            for (int mt = 0; mt < 4; ++mt)
                #pragma unroll
                for (int j = 0; j < 4; ++j) {
                    float e = (mt == 3 && g == 3)
                                  ? 0.f
                                  : exp2f(acc2[mt][nb][j] * 0.1803368801111137f);
                    acc2[mt][nb][j] = e;
                    sum += e;
                }
            sum += __shfl_xor(sum, 16);
            sum += __shfl_xor(sum, 32);
            float inv = 1.f / sum;
            #pragma unroll
            for (int mt = 0; mt < 4; ++mt)
                #pragma unroll
                for (int j = 0; j < 4; ++j) acc2[mt][nb][j] *= inv;
        }
        MKFR_H(pf, false);
    }
    // qf, kf dead here.

    // ---- v = x * WvT + bv   (A = x preloaded once, shared across halves)
    {
        float bcol[4];
        #pragma unroll
        for (int nt = 0; nt < 4; ++nt) bcol[nt] = bv[16 * nt + lo];
        STAGE_A(XFRAG(t), WFRAG(2, nt),
                ((f4){bcol[nt], bcol[nt], bcol[nt], bcol[nt]}), vf, false);
    }

    // ---- weightedT = vT * P, per half (A = vf regs, B = pf regs)
    #pragma unroll
    for (int h = 0; h < 2; ++h) {
        GEMM_R(vf, pf[nt][ks], zc);
        MKFR_H(wtf, false);
    }
    // vf, pf dead here.

    // ---- h1T = relu(W1 * weightedT + b1)   (W1 pi-permuted, A preloaded)
    #pragma unroll
    for (int mt = 0; mt < 4; ++mt) brow[mt] = *(const f4*)&b1[16 * mt + 4 * g];
    STAGE_A(WFRAG(3, t), wtf[nt][ks], brow[mt], h1f, true);

    // ---- h2T = relu(W2 * h1T + b2), head folded per half on f32 acc
    #pragma unroll
    for (int mt = 0; mt < 4; ++mt) brow[mt] = *(const f4*)&b2[16 * mt + 4 * g];
    f4 w3r[4];
    #pragma unroll
    for (int mt = 0; mt < 4; ++mt) w3r[mt] = *(const f4*)&W3[16 * mt + 4 * g];
    float b3v = b3[0];
    {
        half8 afr2[4][2];
        #pragma unroll
        for (int t = 0; t < 4; ++t)
            #pragma unroll
            for (int ks = 0; ks < 2; ++ks) afr2[t][ks] = WFRAG(4, t);
        #pragma unroll
        for (int h = 0; h < 2; ++h) {
            GEMM_R(afr2, h1f[nt][ks], brow[mt]);
            #pragma unroll
            for (int nb = 0; nb < 2; ++nb) {
                float sres = 0.f;
                #pragma unroll
                for (int mt = 0; mt < 4; ++mt)
                    #pragma unroll
                    for (int j = 0; j < 4; ++j)
                        sres += fmaxf(acc2[mt][nb][j], 0.f) * w3r[mt][j];
                sres += __shfl_xor(sres, 16);
                sres += __shfl_xor(sres, 32);
                if (g == 0) {
                    int s = 16 * (2 * h + nb) + lo;
                    if (s < 60) out[(size_t)part * 60 + s] = sres + b3v;
                }
            }
        }
    }
}

extern "C" void kernel_launch(void* const* d_in, const int* in_sizes, int n_in,
                              void* d_out, int out_size, void* d_ws, size_t ws_size,
                              hipStream_t stream) {
    const float* x  = (const float*)d_in[0];
    const float* Wq = (const float*)d_in[1];
    const float* bq = (const float*)d_in[2];
    const float* Wk = (const float*)d_in[3];
    const float* bk = (const float*)d_in[4];
    const float* Wv = (const float*)d_in[5];
    const float* bv = (const float*)d_in[6];
    const float* W1 = (const float*)d_in[7];
    const float* b1 = (const float*)d_in[8];
    const float* W2 = (const float*)d_in[9];
    const float* b2 = (const float*)d_in[10];
    const float* W3 = (const float*)d_in[11];
    const float* b3 = (const float*)d_in[12];
    _Float16* wsH = (_Float16*)d_ws;  // 5 * 4096 halves = 40 KB

    prep_weights<<<80, 256, 0, stream>>>(Wq, Wk, Wv, W1, W2, wsH);
    // 1280 WGs x 512 thr = 8 waves/WG, one part per wave; weights + per-wave
    // x tiles in LDS (100 KB); no spill (VGPR 116). Session champion.
    fused_f16<<<1280, 512, 0, stream>>>(x, wsH, bq, bk, bv, b1, b2, W3, b3,
                                        (float*)d_out);
}